// Round 4
// baseline (216.952 us; speedup 1.0000x reference)
//
#include <hip/hip_runtime.h>

#define BATCH   8
#define LENGTH  4096
#define IN_DIM  512
#define STATE   256
#define OUT_DIM 512
#define NC      64
#define LC      64

typedef __attribute__((ext_vector_type(8)))  short bf16x8;
typedef __attribute__((ext_vector_type(16))) float f32x16;

union FragU { bf16x8 v; unsigned u[4]; };

__device__ __forceinline__ unsigned short bf16_rne(float v) {
    unsigned u = __builtin_bit_cast(unsigned, v);
    unsigned r = (u + 0x7FFFu + ((u >> 16) & 1u)) >> 16;
    return (unsigned short)r;
}
__device__ __forceinline__ float bf16_f(unsigned short h) {
    unsigned u = ((unsigned)h) << 16;
    return __builtin_bit_cast(float, u);
}

// ---------------------------------------------------------------------------
// Split + transpose a weight: in[K][Nsrc] fp32 -> hi/lo bf16 [Nsrc][K] (RNE).
// ---------------------------------------------------------------------------
__global__ __launch_bounds__(256) void split_T_kernel(
    const float* __restrict__ in, unsigned short* __restrict__ hi,
    unsigned short* __restrict__ lo, int kbits, int Nsrc)
{
    int id = blockIdx.x * 256 + threadIdx.x;
    int k = id & ((1 << kbits) - 1);
    int n = id >> kbits;
    float v = in[(size_t)k * Nsrc + n];
    unsigned short h = bf16_rne(v);
    hi[id] = h;
    lo[id] = bf16_rne(v - bf16_f(h));
}

// ---------------------------------------------------------------------------
// Split-bf16 MFMA GEMM (LDS-traffic-optimized retile):
//   C[M][N] = A[M][K] (fp32, split in-register) * Bt[N][K] (hi/lo bf16 planes)
//   acc += Ahi*Bhi + Alo*Bhi + Ahi*Blo  (fp32 accumulate)
// Block: 256 thr = 4 waves, wave-tile 64x64 (2x2 of 32x32), tile 128x128,
// BK=32, mfma_f32_32x32x16_bf16. LDS dbuf 2 x 32KB, raw-barrier + vmcnt(8).
// Per block-iter LDS traffic: 64KB read + 32KB write (vs 128KB in round 3) ->
// MFMA-bound per cycle model.
//
// A plane: 128 rows x 32 fp32 (128B row = 8 slots of 16B); phys = l ^ (row&7).
// B planes: 128 rows x 32 bf16 (64B row = 4 slots);      phys = l ^ ((row>>1)&3).
// Staging inverts the swizzle on the GLOBAL side so each global_load_lds dst
// is wave-uniform-base + lane*16 (HW requirement).
// ---------------------------------------------------------------------------
__global__ __launch_bounds__(256, 2) void gemm_dbuf(
    const float* __restrict__ Af, const unsigned short* __restrict__ Bthi,
    const unsigned short* __restrict__ Btlo, float* __restrict__ Cc,
    int N_, int K)
{
    __shared__ unsigned short lds[2 * 16384];   // 64 KB

    const int tid  = threadIdx.x;
    const int wave = tid >> 6;
    const int lane = tid & 63;
    const int n0 = blockIdx.x * 128;
    const int m0 = blockIdx.y * 128;

    // --- staging: 32 chunks of 1KB per buffer; wave w takes chunks w*8..w*8+7
    const char* gp[8];
    int ldsoff[8], gstep[8];
    #pragma unroll
    for (int t = 0; t < 8; ++t) {
        int gi = wave * 8 + t;
        if (gi < 16) {          // A plane: 16 KB fp32
            int p = gi * 64 + lane;
            int row = p >> 3, s = p & 7;
            int l = s ^ (row & 7);
            gp[t] = (const char*)(Af + (size_t)(m0 + row) * K + l * 4);
            gstep[t] = 32 * 4;              // BK fp32 = 128 B
            ldsoff[t] = gi * 512;           // ushort units
        } else {                // B planes: 8 KB each
            int q2 = (gi - 16) >> 3;        // 0 = hi, 1 = lo
            int pi = (gi - 16) & 7;
            int p = pi * 64 + lane;
            int row = p >> 2, s = p & 3;
            int l = s ^ ((row >> 1) & 3);
            const unsigned short* base = q2 ? Btlo : Bthi;
            gp[t] = (const char*)(base + (size_t)(n0 + row) * K + l * 8);
            gstep[t] = 32 * 2;              // BK bf16 = 64 B
            ldsoff[t] = 8192 + q2 * 4096 + pi * 512;
        }
    }

    const int l31 = lane & 31, q2 = lane >> 5;
    const int wm = (wave >> 1) * 64, wn = (wave & 1) * 64;

    // A frag read offsets (ushort units): [mi][ks][h]; 8 fp32 per lane per frag
    int aoff[2][2][2];
    #pragma unroll
    for (int mi = 0; mi < 2; ++mi) {
        int row = wm + mi * 32 + l31;
        #pragma unroll
        for (int ks = 0; ks < 2; ++ks)
            #pragma unroll
            for (int h = 0; h < 2; ++h)
                aoff[mi][ks][h] = row * 64 + ((ks * 4 + q2 * 2 + h) ^ (row & 7)) * 8;
    }
    // B frag read offsets: [nj][ks]; one 16B slot = full bf16 frag
    int boff[2][2];
    #pragma unroll
    for (int nj = 0; nj < 2; ++nj) {
        int row = wn + nj * 32 + l31;
        #pragma unroll
        for (int ks = 0; ks < 2; ++ks)
            boff[nj][ks] = row * 32 + (((ks * 2 + q2) ^ ((row >> 1) & 3))) * 8;
    }

    f32x16 acc[2][2];
    #pragma unroll
    for (int mi = 0; mi < 2; ++mi)
        #pragma unroll
        for (int nj = 0; nj < 2; ++nj)
            #pragma unroll
            for (int r = 0; r < 16; ++r) acc[mi][nj][r] = 0.f;

    // prologue: stage buffer 0
    #pragma unroll
    for (int t = 0; t < 8; ++t) {
        __builtin_amdgcn_global_load_lds(
            (const __attribute__((address_space(1))) unsigned*)(gp[t]),
            (__attribute__((address_space(3))) unsigned*)(&lds[ldsoff[t]]),
            16, 0, 0);
        gp[t] += gstep[t];
    }

    const int nit = K >> 5;
    for (int it = 0; it < nit; ++it) {
        asm volatile("" ::: "memory");
        __builtin_amdgcn_s_barrier();       // all waves done computing other buf
        asm volatile("" ::: "memory");
        if (it + 1 < nit) {
            const int bb = ((it + 1) & 1) * 16384;
            #pragma unroll
            for (int t = 0; t < 8; ++t) {
                __builtin_amdgcn_global_load_lds(
                    (const __attribute__((address_space(1))) unsigned*)(gp[t]),
                    (__attribute__((address_space(3))) unsigned*)(&lds[bb + ldsoff[t]]),
                    16, 0, 0);
                gp[t] += gstep[t];
            }
            __builtin_amdgcn_s_waitcnt(0x0F78);   // vmcnt(8): cur buf done, prefetch flying
        } else {
            __builtin_amdgcn_s_waitcnt(0x0F70);   // vmcnt(0)
        }
        asm volatile("" ::: "memory");
        __builtin_amdgcn_s_barrier();             // current buf visible to all
        asm volatile("" ::: "memory");

        const unsigned short* buf = &lds[(it & 1) * 16384];

        #pragma unroll
        for (int ks = 0; ks < 2; ++ks) {
            // A fragments: fp32 -> hi/lo bf16 (trunc split, v_perm packing)
            FragU ahi[2], alo[2];
            #pragma unroll
            for (int mi = 0; mi < 2; ++mi) {
                float4 f0 = *(const float4*)(buf + aoff[mi][ks][0]);
                float4 f1 = *(const float4*)(buf + aoff[mi][ks][1]);
                unsigned b0 = __builtin_bit_cast(unsigned, f0.x);
                unsigned b1 = __builtin_bit_cast(unsigned, f0.y);
                unsigned b2 = __builtin_bit_cast(unsigned, f0.z);
                unsigned b3 = __builtin_bit_cast(unsigned, f0.w);
                unsigned b4 = __builtin_bit_cast(unsigned, f1.x);
                unsigned b5 = __builtin_bit_cast(unsigned, f1.y);
                unsigned b6 = __builtin_bit_cast(unsigned, f1.z);
                unsigned b7 = __builtin_bit_cast(unsigned, f1.w);
                ahi[mi].u[0] = __builtin_amdgcn_perm(b1, b0, 0x07060302);
                ahi[mi].u[1] = __builtin_amdgcn_perm(b3, b2, 0x07060302);
                ahi[mi].u[2] = __builtin_amdgcn_perm(b5, b4, 0x07060302);
                ahi[mi].u[3] = __builtin_amdgcn_perm(b7, b6, 0x07060302);
                float l0 = f0.x - __builtin_bit_cast(float, b0 & 0xFFFF0000u);
                float l1 = f0.y - __builtin_bit_cast(float, b1 & 0xFFFF0000u);
                float l2 = f0.z - __builtin_bit_cast(float, b2 & 0xFFFF0000u);
                float l3 = f0.w - __builtin_bit_cast(float, b3 & 0xFFFF0000u);
                float l4 = f1.x - __builtin_bit_cast(float, b4 & 0xFFFF0000u);
                float l5 = f1.y - __builtin_bit_cast(float, b5 & 0xFFFF0000u);
                float l6 = f1.z - __builtin_bit_cast(float, b6 & 0xFFFF0000u);
                float l7 = f1.w - __builtin_bit_cast(float, b7 & 0xFFFF0000u);
                alo[mi].u[0] = __builtin_amdgcn_perm(
                    __builtin_bit_cast(unsigned, l1), __builtin_bit_cast(unsigned, l0), 0x07060302);
                alo[mi].u[1] = __builtin_amdgcn_perm(
                    __builtin_bit_cast(unsigned, l3), __builtin_bit_cast(unsigned, l2), 0x07060302);
                alo[mi].u[2] = __builtin_amdgcn_perm(
                    __builtin_bit_cast(unsigned, l5), __builtin_bit_cast(unsigned, l4), 0x07060302);
                alo[mi].u[3] = __builtin_amdgcn_perm(
                    __builtin_bit_cast(unsigned, l7), __builtin_bit_cast(unsigned, l6), 0x07060302);
            }
            FragU bhi[2], blo[2];
            #pragma unroll
            for (int nj = 0; nj < 2; ++nj) {
                bhi[nj].v = *(const bf16x8*)(buf +  8192 + boff[nj][ks]);
                blo[nj].v = *(const bf16x8*)(buf + 12288 + boff[nj][ks]);
            }
            #pragma unroll
            for (int mi = 0; mi < 2; ++mi)
                #pragma unroll
                for (int nj = 0; nj < 2; ++nj) {
                    acc[mi][nj] = __builtin_amdgcn_mfma_f32_32x32x16_bf16(
                        ahi[mi].v, bhi[nj].v, acc[mi][nj], 0, 0, 0);
                    acc[mi][nj] = __builtin_amdgcn_mfma_f32_32x32x16_bf16(
                        alo[mi].v, bhi[nj].v, acc[mi][nj], 0, 0, 0);
                    acc[mi][nj] = __builtin_amdgcn_mfma_f32_32x32x16_bf16(
                        ahi[mi].v, blo[nj].v, acc[mi][nj], 0, 0, 0);
                }
        }
    }

    // epilogue: 32x32 C/D layout [m74/m101]: col = lane&31,
    // row = (reg&3) + 8*(reg>>2) + 4*(lane>>5)
    #pragma unroll
    for (int mi = 0; mi < 2; ++mi)
        #pragma unroll
        for (int nj = 0; nj < 2; ++nj) {
            #pragma unroll
            for (int r = 0; r < 16; ++r) {
                int row_g = m0 + wm + mi * 32 + 4 * q2 + (r & 3) + 8 * (r >> 2);
                int col_g = n0 + wn + nj * 32 + l31;
                Cc[(size_t)row_g * N_ + col_g] = acc[mi][nj][r];
            }
        }
}

// ---------------------------------------------------------------------------
// Scan phase A: per-chunk carry with zero initial state.
// ---------------------------------------------------------------------------
__global__ __launch_bounds__(256) void scan_carry(
    const float* __restrict__ uB, const float* __restrict__ A,
    float* __restrict__ carry)
{
    const int b = blockIdx.x;
    const int c = blockIdx.y;
    const int n = threadIdx.x;
    const float a = A[n];
    const float* p = uB + ((size_t)b * LENGTH + (size_t)c * LC) * STATE + n;
    float s = 0.f;
    #pragma unroll 8
    for (int j = 0; j < LC; ++j) s = a * s + p[(size_t)j * STATE];
    carry[((size_t)b * NC + c) * STATE + n] = s;
}

// ---------------------------------------------------------------------------
// Scan phase B (fused combine+apply): rebuild entry state from carries,
// re-apply recurrence, write x fp32 (+ x_last from last chunk).
// ---------------------------------------------------------------------------
__global__ __launch_bounds__(256) void scan_apply(
    const float* __restrict__ uB, const float* __restrict__ A,
    const float* __restrict__ carry, const float* __restrict__ x0,
    float* __restrict__ x, float* __restrict__ x_last)
{
    const int b = blockIdx.x;
    const int c = blockIdx.y;
    const int n = threadIdx.x;
    const float a = A[n];
    float a2 = a * a, a4 = a2 * a2, a8 = a4 * a4, a16 = a8 * a8, a32 = a16 * a16;
    const float aLC = a32 * a32;   // a^64

    float s = x0[(size_t)b * STATE + n];
    for (int d = 0; d < c; ++d)
        s = aLC * s + carry[((size_t)b * NC + d) * STATE + n];

    const size_t base = ((size_t)b * LENGTH + (size_t)c * LC) * STATE + n;
    const float* p = uB + base;
    float* qx = x + base;
    #pragma unroll 8
    for (int j = 0; j < LC; ++j) {
        s = a * s + p[(size_t)j * STATE];
        qx[(size_t)j * STATE] = s;
    }
    if (c == NC - 1) x_last[(size_t)b * STATE + n] = s;
}

// ---------------------------------------------------------------------------
extern "C" void kernel_launch(void* const* d_in, const int* in_sizes, int n_in,
                              void* d_out, int out_size, void* d_ws, size_t ws_size,
                              hipStream_t stream)
{
    const float* u  = (const float*)d_in[0];   // [8,4096,512]
    const float* x0 = (const float*)d_in[1];   // [8,256]
    const float* A  = (const float*)d_in[2];   // [256]
    const float* B  = (const float*)d_in[3];   // [512,256]
    const float* C  = (const float*)d_in[4];   // [256,512]

    const size_t MB = 1024 * 1024;
    char* ws = (char*)d_ws;

    float* x     = (float*)(ws);                               // [M,256] fp32, 32 MB
    float* carry = (float*)(ws + 32 * MB);                     // 512 KB
    unsigned short* Bt_hi = (unsigned short*)(ws + 33 * MB);                // 256 KB
    unsigned short* Bt_lo = (unsigned short*)(ws + 33 * MB + 256 * 1024);   // 256 KB
    unsigned short* Ct_hi = (unsigned short*)(ws + 33 * MB + 512 * 1024);   // 256 KB
    unsigned short* Ct_lo = (unsigned short*)(ws + 33 * MB + 768 * 1024);   // 256 KB

    float* y      = (float*)d_out;                             // [8,4096,512] = 64 MB
    float* x_last = y + (size_t)BATCH * LENGTH * OUT_DIM;      // [8,256]
    // uB parks in upper half of y's region; dead before GEMM2 writes y.
    float* uB     = (float*)((char*)d_out + 32 * MB);          // [M,256] = 32 MB

    const int M = BATCH * LENGTH;   // 32768

    // 1. split+transpose weights to bf16 hi/lo planes
    split_T_kernel<<<dim3((IN_DIM * STATE) / 256), dim3(256), 0, stream>>>(B, Bt_hi, Bt_lo, 9, STATE);
    split_T_kernel<<<dim3((STATE * OUT_DIM) / 256), dim3(256), 0, stream>>>(C, Ct_hi, Ct_lo, 8, OUT_DIM);

    // 2. GEMM1: uB[M,256] = u[M,512] @ B
    gemm_dbuf<<<dim3(STATE / 128, M / 128), dim3(256), 0, stream>>>(
        u, Bt_hi, Bt_lo, uB, STATE, IN_DIM);

    // 3. chunked scan (fp32 exact)
    scan_carry<<<dim3(BATCH, NC), dim3(256), 0, stream>>>(uB, A, carry);
    scan_apply<<<dim3(BATCH, NC), dim3(256), 0, stream>>>(uB, A, carry, x0, x, x_last);

    // 4. GEMM2: y[M,512] = x[M,256] @ C
    gemm_dbuf<<<dim3(OUT_DIM / 128, M / 128), dim3(256), 0, stream>>>(
        x, Ct_hi, Ct_lo, y, OUT_DIM, STATE);
}